// Round 1
// 93.842 us; speedup vs baseline: 1.0063x; 1.0063x over previous
//
#include <hip/hip_runtime.h>

#define HW 4096   // 64*64 pixels per (b,c) image

typedef float f4 __attribute__((ext_vector_type(4)));
typedef float f2 __attribute__((ext_vector_type(2)));

// ---------------------------------------------------------------------------
// proj v7: LDS-staged input tile + packed-f32 FMA.
// grid = 768 = 6 slices x 128 pair-blocks; slice sp = (matrix m, cout-half).
// Each block stages its 64ch x 128px source tile (32 KB LDS) ONCE; the 4
// waves each compute 8 couts from LDS (g wave-uniform via readfirstlane so
// weight addresses stay on the scalar pipe -> s_load, as in v6).
// Inner math is f2-vector fma -> v_pk_fma_f32: halves VALU vs v6's scalar
// fmaf (1024 -> 512 insts/thread). L2 read traffic: 96 MB (v6's 8x re-read)
// -> 24 MB (4 blocks share each x tile, 2 share each y tile).
// 3 blocks/CU (96 KB LDS), ~50 VGPR: no spill.
// ---------------------------------------------------------------------------
__global__ __launch_bounds__(256) void proj_kernel(
    const float* __restrict__ x, const float* __restrict__ y,
    const float* __restrict__ Wq, const float* __restrict__ Wk,
    const float* __restrict__ Wv,
    float* __restrict__ qkv)     // q | k | v, each 1<<20 floats
{
    __shared__ float xT[64 * 128];          // [cin][px], 32 KB

    const int pb   = blockIdx.x & 127;      // pair-block: 64 pairs = 128 px
    const int sp   = blockIdx.x >> 7;       // 0..5 (uniform)
    const int m    = sp >> 1;               // matrix 0=q 1=k 2=v
    const int half = sp & 1;                // cout half (32 couts)
    const int t    = threadIdx.x;

    const int b   = pb >> 5;                // 32 pair-blocks per batch image
    const int pp0 = (pb & 31) * 128;        // pixel base within image

    const float* W   = (m == 0) ? Wq : (m == 1) ? Wk : Wv;   // uniform
    const float* src = (m == 2) ? y : x;                     // uniform
    const float* sb0 = src + (size_t)b * 64 * HW + pp0;

    // ---- stage: 64 ch x 128 px = 2048 f4 chunks, 8 per thread, coalesced
#pragma unroll
    for (int i = 0; i < 8; ++i) {
        const int chunk = i * 256 + t;      // 0..2047
        const int c = chunk >> 5;           // channel
        const int o = (chunk & 31) * 4;     // px offset within tile row
        *(f4*)&xT[c * 128 + o] = *(const f4*)&sb0[c * HW + o];
    }
    __syncthreads();

    // ---- compute: wave g handles couts r0..r0+7, lane p handles px pair p
    const int g  = __builtin_amdgcn_readfirstlane(t >> 6);   // wave-uniform
    const int p  = t & 63;
    const int r0 = half * 32 + g * 8;

    f2 acc[8];
#pragma unroll
    for (int j = 0; j < 8; ++j) acc[j] = (f2){0.f, 0.f};

#pragma unroll
    for (int cb = 0; cb < 8; ++cb) {        // 8 chunks of 8 input channels
        f2 xs[8];
#pragma unroll
        for (int c2 = 0; c2 < 8; ++c2)
            xs[c2] = *(const f2*)&xT[(cb * 8 + c2) * 128 + p * 2];
#pragma unroll
        for (int j = 0; j < 8; ++j) {
            const float* wr = W + (r0 + j) * 64 + cb * 8;    // uniform -> s_load
#pragma unroll
            for (int c2 = 0; c2 < 8; ++c2) {
                const f2 w2 = {wr[c2], wr[c2]};
                acc[j] = __builtin_elementwise_fma(w2, xs[c2], acc[j]);
            }
        }
    }

    float* dstm = qkv + ((size_t)m << 20) + (size_t)b * 64 * HW + pp0;
#pragma unroll
    for (int j = 0; j < 8; ++j)
        *(f2*)&dstm[(size_t)(r0 + j) * HW + p * 2] = acc[j];
}

// ---------------------------------------------------------------------------
// attn v5 (unchanged — at its transcendental floor: 49 exp2/output, trans
// pipe 1568 cy/wave > VALU 1400 cy/wave). per-channel 7x7 window attention,
// LDS k/v tile with zero halo. Inner op: fma + exp2 + add + fma.
// No clamp: |log2e*q*(k+bias)| < ~100 << 128 -> exp2 overflow impossible.
// grid = 1024 (b, c, 16-row band), block 256, thread = 4 px.
// ---------------------------------------------------------------------------
__global__ __launch_bounds__(256) void attn_kernel(
    const float* __restrict__ qg, const float* __restrict__ kg,
    const float* __restrict__ vg,
    const float* __restrict__ rel_h, const float* __restrict__ rel_w,
    float* __restrict__ out)
{
    __shared__ float kT[22 * 72];
    __shared__ float vT[22 * 72];

    const int blk = blockIdx.x;
    const int bc  = blk >> 2;            // b*64 + c
    const int h0  = (blk & 3) << 4;
    const int c   = bc & 63;
    const int t   = threadIdx.x;

    const float* kimg = kg + (size_t)bc * HW;
    const float* vimg = vg + (size_t)bc * HW;
    const f4 z4 = {0.f, 0.f, 0.f, 0.f};

    if (t < 88) {                        // horizontal halo zero
        const int row = t >> 2, side = (t >> 1) & 1, arr = t & 1;
        float* dst = arr ? vT : kT;
        *(f4*)&dst[row * 72 + side * 68] = z4;
    }
#pragma unroll
    for (int j = 0; j < 2; ++j) {        // interior: 22 rows x 16 f4 chunks
        const int idx = j * 256 + t;
        if (idx < 352) {
            const int row = idx >> 4, ch = idx & 15;
            const int hy = h0 - 3 + row;
            const bool rv = ((unsigned)hy < 64u);
            const f4 kv = rv ? *(const f4*)&kimg[hy * 64 + ch * 4] : z4;
            const f4 vv = rv ? *(const f4*)&vimg[hy * 64 + ch * 4] : z4;
            *(f4*)&kT[row * 72 + ch * 4 + 4] = kv;
            *(f4*)&vT[row * 72 + ch * 4 + 4] = vv;
        }
    }
    __syncthreads();

    const int r  = t >> 4;               // 0..15
    const int w0 = (t & 15) << 2;
    const int h  = h0 + r;

    const float LOG2E = 1.4426950408889634f;
    const f4 qv = *(const f4*)&qg[(size_t)bc * HW + h * 64 + w0];
    float qe[4];
#pragma unroll
    for (int p = 0; p < 4; ++p) qe[p] = qv[p] * LOG2E;

    float qb[7][4];
    if (c < 32) {
#pragma unroll
        for (int a = 0; a < 7; ++a) {
            const float bb = rel_h[c * 7 + a];
#pragma unroll
            for (int p = 0; p < 4; ++p) qb[a][p] = qe[p] * bb;
        }
    } else {
#pragma unroll
        for (int j = 0; j < 7; ++j) {
            const float bb = rel_w[(c - 32) * 7 + j];
#pragma unroll
            for (int p = 0; p < 4; ++p) qb[j][p] = qe[p] * bb;
        }
    }

    float l[4] = {0.f, 0.f, 0.f, 0.f};
    float o[4] = {0.f, 0.f, 0.f, 0.f};

    if (c < 32) {
#pragma unroll
        for (int a = 0; a < 7; ++a) {
            const int ro = (r + a) * 72 + w0;
            const f4 k0 = *(const f4*)&kT[ro];
            const f4 k1 = *(const f4*)&kT[ro + 4];
            const f4 k2 = *(const f4*)&kT[ro + 8];
            const f4 v0 = *(const f4*)&vT[ro];
            const f4 v1 = *(const f4*)&vT[ro + 4];
            const f4 v2 = *(const f4*)&vT[ro + 8];
            const float kw[12] = {k0[0], k0[1], k0[2], k0[3], k1[0], k1[1], k1[2], k1[3],
                                  k2[0], k2[1], k2[2], k2[3]};
            const float vw[12] = {v0[0], v0[1], v0[2], v0[3], v1[0], v1[1], v1[2], v1[3],
                                  v2[0], v2[1], v2[2], v2[3]};
#pragma unroll
            for (int b2 = 0; b2 < 7; ++b2)
#pragma unroll
                for (int p = 0; p < 4; ++p) {
                    const float s = fmaf(qe[p], kw[p + b2 + 1], qb[a][p]);
                    const float e = __builtin_amdgcn_exp2f(s);
                    l[p] += e;
                    o[p] = fmaf(e, vw[p + b2 + 1], o[p]);
                }
        }
    } else {
#pragma unroll
        for (int a = 0; a < 7; ++a) {
            const int ro = (r + a) * 72 + w0;
            const f4 k0 = *(const f4*)&kT[ro];
            const f4 k1 = *(const f4*)&kT[ro + 4];
            const f4 k2 = *(const f4*)&kT[ro + 8];
            const f4 v0 = *(const f4*)&vT[ro];
            const f4 v1 = *(const f4*)&vT[ro + 4];
            const f4 v2 = *(const f4*)&vT[ro + 8];
            const float kw[12] = {k0[0], k0[1], k0[2], k0[3], k1[0], k1[1], k1[2], k1[3],
                                  k2[0], k2[1], k2[2], k2[3]};
            const float vw[12] = {v0[0], v0[1], v0[2], v0[3], v1[0], v1[1], v1[2], v1[3],
                                  v2[0], v2[1], v2[2], v2[3]};
#pragma unroll
            for (int b2 = 0; b2 < 7; ++b2)
#pragma unroll
                for (int p = 0; p < 4; ++p) {
                    const float s = fmaf(qe[p], kw[p + b2 + 1], qb[b2][p]);
                    const float e = __builtin_amdgcn_exp2f(s);
                    l[p] += e;
                    o[p] = fmaf(e, vw[p + b2 + 1], o[p]);
                }
        }
    }

    f4 res;
#pragma unroll
    for (int p = 0; p < 4; ++p)
        res[p] = o[p] * __builtin_amdgcn_rcpf(l[p]);
    *(f4*)&out[(size_t)bc * HW + h * 64 + w0] = res;
}

// ---------------------------------------------------------------------------
extern "C" void kernel_launch(void* const* d_in, const int* in_sizes, int n_in,
                              void* d_out, int out_size, void* d_ws, size_t ws_size,
                              hipStream_t stream) {
    const float* x   = (const float*)d_in[0];
    const float* y   = (const float*)d_in[1];
    const float* Wq  = (const float*)d_in[2];
    const float* Wk  = (const float*)d_in[3];
    const float* Wv  = (const float*)d_in[4];
    const float* rlh = (const float*)d_in[5];
    const float* rlw = (const float*)d_in[6];
    float* out = (float*)d_out;

    float* qkv = (float*)d_ws;        // q | k | v, 4 MB each, contiguous
    float* q = qkv;
    float* k = qkv + (1 << 20);
    float* v = qkv + (2 << 20);

    proj_kernel<<<768, 256, 0, stream>>>(x, y, Wq, Wk, Wv, qkv);
    attn_kernel<<<1024, 256, 0, stream>>>(q, k, v, rlh, rlw, out);
}